// Round 8
// baseline (411.596 us; speedup 1.0000x reference)
//
#include <hip/hip_runtime.h>

// Problem constants
#define HDIM 256
#define WDIM 1216
#define HWC  (HDIM*WDIM)     // 311296
#define NPTS 40000
#define KNN  9
#define PIXR 256             // index range of pixel coords (0..255)
#define EPSF 1e-5f

typedef __attribute__((ext_vector_type(8))) short bf16x8;
typedef __attribute__((ext_vector_type(4))) float f32x4;

static __device__ __forceinline__ unsigned short f2bf(float f) {
    unsigned int u = __float_as_uint(f);
    u += 0x7FFFu + ((u >> 16) & 1u);     // round-nearest-even
    return (unsigned short)(u >> 16);
}

// ---------------------------------------------------------------------------
// Kernel 1: prep — feature transpose (1024 blocks) + workspace init side-jobs
// (winner=-1, sums=0). Init completes before point_k launches (stream order),
// so the atomicMax consumer moved to point_k is safe. No memset dispatches.
// ---------------------------------------------------------------------------
__global__ __launch_bounds__(256) void prep_k(const float* __restrict__ feat,
                                              float* __restrict__ feat_t,
                                              int* __restrict__ winner,
                                              float* __restrict__ sums) {
    __shared__ float tile[64][65];
    const int iy   = blockIdx.x >> 2;
    const int ixb  = (blockIdx.x & 3) * 64;
    const int lane = threadIdx.x & 63;
    const int w    = threadIdx.x >> 6;

    // init side-jobs (disjoint from transpose writes)
    const int tid = blockIdx.x * 256 + threadIdx.x;
    if (tid < PIXR * PIXR) winner[tid] = -1;
    if (tid < 128) sums[tid] = 0.f;

#pragma unroll
    for (int r = 0; r < 16; ++r) {
        int cc = w * 16 + r;
        tile[cc][lane] = feat[cc * HWC + iy * WDIM + ixb + lane];   // 256B coalesced
    }
    __syncthreads();
#pragma unroll
    for (int r = 0; r < 16; ++r) {
        int ix = w * 16 + r;
        feat_t[(iy * PIXR + ixb + ix) * 64 + lane] = tile[lane][ix]; // 256B coalesced
    }
}

// ---------------------------------------------------------------------------
// Kernel 2: MFMA point kernel. ONE WAVE per block, 4 points per wave,
// grid 10000 -> ~9.8 waves/SIMD available (was 2.4 at 16 pts/wave): the
// per-point serial chain (gather -> LDS hmid -> MFMA -> LDS reduce) is now
// hidden by TLP instead of exposed. MFMA fragment layouts identical to R7
// (proven). Phase C conv tile uses rows 0..3 only (quad 0 stores/accumulates).
// Also absorbs the winner atomicMax side-job (after prep_k's init).
// ---------------------------------------------------------------------------
__global__ __launch_bounds__(64) void point_k(
    const float* __restrict__ feat_t,   // [256*256, 64]
    const float* __restrict__ diff,     // [N, 9, 3]
    const int*   __restrict__ nnpix,    // [N, 9, 2]
    const int*   __restrict__ pix,      // [N, 2]
    const float* __restrict__ W1,       // [3, 32]
    const float* __restrict__ b1,       // [32]
    const float* __restrict__ W2,       // [32, 64]
    const float* __restrict__ b2,       // [64]
    const float* __restrict__ conv_w,   // [64, 64] (out, in)
    const float* __restrict__ conv_b,   // [64]
    int*   __restrict__ winner,         // [256*256]
    float* __restrict__ y_buf,          // [N, 64]
    float* __restrict__ sums)           // [128]
{
    __shared__ float dstage[112];            // diff for 4 points (108 used)
    __shared__ int   npx[80];                // nnpix for 4 points (72 used)
    __shared__ unsigned int hl[320];         // hmid [16 rows][20 u32], 80B row stride
    __shared__ float part[256];              // [64 c'][4 quads]
    __shared__ unsigned short msgst[1152];   // msg [16 rows][72 u16]; rows 0-3 valid

    const int l   = threadIdx.x;
    const int q   = l >> 4;
    const int col = l & 15;
    const int nbase = blockIdx.x * 4;

    // winner side-job: last-wins per output pixel (init done by prep_k)
    if (l < 4) {
        int px = pix[(nbase + l) * 2];
        int py = pix[(nbase + l) * 2 + 1];
        atomicMax(&winner[py * PIXR + px], nbase + l);
    }

    // ---- persistent fragments (loaded once) ----
    // W2 B-frag: B[j = 8q+t][c' = col+16m]
    bf16x8 bw2[4];
#pragma unroll
    for (int m = 0; m < 4; ++m)
#pragma unroll
        for (int t = 0; t < 8; ++t)
            bw2[m][t] = (short)f2bf(W2[(q * 8 + t) * 64 + col + 16 * m]);
    // conv B-frag: B[c' = 32h+8q+t][c = col+16m] = conv_w[c][c']
    bf16x8 bcv[4][2];
#pragma unroll
    for (int m = 0; m < 4; ++m)
#pragma unroll
        for (int h = 0; h < 2; ++h)
#pragma unroll
            for (int t = 0; t < 8; ++t)
                bcv[m][h][t] = (short)f2bf(conv_w[(col + 16 * m) * 64 + h * 32 + q * 8 + t]);

    float b2m[4], cbm[4];
#pragma unroll
    for (int m = 0; m < 4; ++m) { b2m[m] = b2[col + 16 * m]; cbm[m] = conv_b[col + 16 * m]; }

    // W1 columns for phase A (j0 = 2*col, j0+1)
    const int j0 = 2 * col;
    const float wa0 = W1[j0],     wa1 = W1[32 + j0],     wa2 = W1[64 + j0],     ba = b1[j0];
    const float wb0 = W1[j0 + 1], wb1 = W1[32 + j0 + 1], wb2 = W1[64 + j0 + 1], bb = b1[j0 + 1];

    // preload diff (108 f32) + nnpix (72 i32) for the wave's 4 points
    if (l < 64) dstage[l] = diff[nbase * 27 + l];
    if (l < 44) dstage[l + 64] = diff[nbase * 27 + l + 64];
    npx[l] = nnpix[nbase * 18 + l];
    if (l < 8) npx[l + 64] = nnpix[nbase * 18 + l + 64];

    // zero hmid pad rows 9..15 (phase A never writes them)
    for (int z = 180 + l; z < 320; z += 64) hl[z] = 0;

    float s1[4] = {0.f, 0.f, 0.f, 0.f}, s2[4] = {0.f, 0.f, 0.f, 0.f};

    for (int g = 0; g < 4; ++g) {
        // --- gather f in D-layout: fval[m][i] = f[n, k=4q+i, c'=col+16m] ---
        float fval[4][4];
#pragma unroll
        for (int i = 0; i < 4; ++i) {
            int k = q * 4 + i;
#pragma unroll
            for (int m = 0; m < 4; ++m) fval[m][i] = 0.f;
            if (k < 9) {
                int px = npx[(g * 9 + k) * 2];
                int py = npx[(g * 9 + k) * 2 + 1];
                const float* fb = feat_t + (py * PIXR + px) * 64 + col;
#pragma unroll
                for (int m = 0; m < 4; ++m) fval[m][i] = fb[16 * m];
            }
        }

        // --- phase A: hmid[k2][2*col, 2*col+1] once per point ---
#pragma unroll
        for (int i2 = 0; i2 < 3; ++i2) {
            int k2 = q + 4 * i2;          // covers k 0..8 exactly
            if (k2 < 9) {
                float d0 = dstage[g * 27 + k2 * 3];
                float d1 = dstage[g * 27 + k2 * 3 + 1];
                float d2 = dstage[g * 27 + k2 * 3 + 2];
                float h0 = fmaxf(fmaf(d0, wa0, fmaf(d1, wa1, fmaf(d2, wa2, ba))), 0.f);
                float h1 = fmaxf(fmaf(d0, wb0, fmaf(d1, wb1, fmaf(d2, wb2, bb))), 0.f);
                hl[k2 * 20 + col] = (unsigned int)f2bf(h0) | ((unsigned int)f2bf(h1) << 16);
            }
        }

        // --- phase B: wts via MFMA, then weighted neighbor sum ---
        bf16x8 a;
        {
            uint4 av = *(const uint4*)((const char*)hl + col * 80 + q * 16);
            a = __builtin_bit_cast(bf16x8, av);
        }
#pragma unroll
        for (int m = 0; m < 4; ++m) {
            f32x4 acc = {b2m[m], b2m[m], b2m[m], b2m[m]};
            acc = __builtin_amdgcn_mfma_f32_16x16x32_bf16(a, bw2[m], acc, 0, 0, 0);
            float p = 0.f;
#pragma unroll
            for (int i = 0; i < 4; ++i)
                p = fmaf(fmaxf(acc[i], 0.f), fval[m][i], p);
            part[(col + 16 * m) * 4 + q] = p;     // quad partials
        }
        float4 pr = *(const float4*)&part[l * 4]; // lane l = channel c'
        float msg = (pr.x + pr.y) + (pr.z + pr.w);
        msgst[g * 72 + l] = f2bf(msg);
    }

    // --- phase C: batched 1x1 conv over the 4 points (rows 0..3 of the tile;
    //     rows 4..15 of msgst are garbage but only affect unused D rows) ---
    bf16x8 am[2];
#pragma unroll
    for (int h = 0; h < 2; ++h) {
        uint4 av = *(const uint4*)((const char*)msgst + col * 144 + h * 64 + q * 16);
        am[h] = __builtin_bit_cast(bf16x8, av);
    }
#pragma unroll
    for (int m = 0; m < 4; ++m) {
        f32x4 acc = {cbm[m], cbm[m], cbm[m], cbm[m]};
        acc = __builtin_amdgcn_mfma_f32_16x16x32_bf16(am[0], bcv[m][0], acc, 0, 0, 0);
        acc = __builtin_amdgcn_mfma_f32_16x16x32_bf16(am[1], bcv[m][1], acc, 0, 0, 0);
        if (q == 0) {                                // D rows 0..3 live in quad 0
#pragma unroll
            for (int i = 0; i < 4; ++i) {
                float y = acc[i];                    // row n_local = i, col c
                y_buf[(nbase + i) * 64 + col + 16 * m] = y;
                s1[m] += y;
                s2[m] = fmaf(y, y, s2[m]);
            }
        }
    }

    // --- BN partials: cross-quad shfl reduce (quads 1-3 hold zeros) ---
#pragma unroll
    for (int m = 0; m < 4; ++m) {
        float a1 = s1[m], a2 = s2[m];
        a1 += __shfl_xor(a1, 16); a1 += __shfl_xor(a1, 32);
        a2 += __shfl_xor(a2, 16); a2 += __shfl_xor(a2, 32);
        if (q == 0) {
            atomicAdd(&sums[col + 16 * m], a1);
            atomicAdd(&sums[64 + col + 16 * m], a2);
        }
    }
}

// ---------------------------------------------------------------------------
// Kernel 3: full-image writer, c-chunked (proven R7). Block = (y row, 16-c
// chunk); winner line kept in VGPR; y_buf chunk line L1-resident across cc.
// ---------------------------------------------------------------------------
__global__ __launch_bounds__(256) void write_k(
    const float* __restrict__ y_buf,   // [N, 64] pre-BN
    const float* __restrict__ sums,    // [128]
    const float* __restrict__ gamma,   // [64]
    const float* __restrict__ beta,    // [64]
    const int*   __restrict__ winner,  // [256*256]
    float* __restrict__ out)           // [64, 256, 1216]
{
    const int y  = blockIdx.x >> 2;
    const int ch = (blockIdx.x & 3) * 16;
    const int t  = threadIdx.x;
    const float inv_n = 1.f / (float)NPTS;

    const int wn = winner[y * PIXR + t];       // coalesced 1KB, kept in VGPR
#pragma unroll
    for (int cc = 0; cc < 16; ++cc) {
        int c = ch + cc;
        float mean = sums[c] * inv_n;
        float var  = sums[64 + c] * inv_n - mean * mean;
        float rstd = rsqrtf(var + EPSF);
        float A = gamma[c] * rstd;
        float B = beta[c] - mean * A;

        float v = 0.f;
        if (wn >= 0) v = fmaxf(fmaf(A, y_buf[wn * 64 + c], B), 0.f);
        float* row = out + c * HWC + y * WDIM;
        row[t] = v;                            // coalesced 1KB
        if (t < 240) {
            float4 z = {0.f, 0.f, 0.f, 0.f};
            ((float4*)(row + 256))[t] = z;     // zero x = 256..1215
        }
    }
}

// ---------------------------------------------------------------------------
extern "C" void kernel_launch(void* const* d_in, const int* in_sizes, int n_in,
                              void* d_out, int out_size, void* d_ws, size_t ws_size,
                              hipStream_t stream) {
    const float* feat   = (const float*)d_in[0];   // [1,64,256,1216]
    const float* diff   = (const float*)d_in[1];   // [1,40000,9,3]
    const int*   pix    = (const int*)  d_in[2];   // [1,40000,2]
    const int*   nnpix  = (const int*)  d_in[3];   // [1,40000,9,2]
    const float* W1     = (const float*)d_in[4];   // [3,32]
    const float* b1v    = (const float*)d_in[5];   // [32]
    const float* W2     = (const float*)d_in[6];   // [32,64]
    const float* b2v    = (const float*)d_in[7];   // [64]
    const float* conv_w = (const float*)d_in[8];   // [64,64]
    const float* conv_b = (const float*)d_in[9];   // [64]
    const float* gamma  = (const float*)d_in[10];  // [64]
    const float* beta   = (const float*)d_in[11];  // [64]
    float* out = (float*)d_out;

    // workspace layout (bytes) — within proven 37.5 MB footprint:
    //   feat_t : 0        .. 16777216    (256*256*64 f32)
    //   y_buf  : 16777216 .. 27017216    (40000*64 f32)
    //   sums   : 27017216 .. 27017728    (128 f32)
    //   winner : 27017728 .. 27279872    (256*256 i32)
    char* ws = (char*)d_ws;
    float* feat_t  = (float*)(ws);
    float* y_buf   = (float*)(ws + 16777216);
    float* sums    = (float*)(ws + 27017216);
    int*   winner  = (int*)  (ws + 27017728);

    prep_k<<<1024, 256, 0, stream>>>(feat, feat_t, winner, sums);
    point_k<<<10000, 64, 0, stream>>>(feat_t, diff, nnpix, pix, W1, b1v, W2, b2v,
                                      conv_w, conv_b, winner, y_buf, sums);
    write_k<<<1024, 256, 0, stream>>>(y_buf, sums, gamma, beta, winner, out);
}

// Round 9
// 237.471 us; speedup vs baseline: 1.7332x; 1.7332x over previous
//
#include <hip/hip_runtime.h>

// Problem constants
#define HDIM 256
#define WDIM 1216
#define HWC  (HDIM*WDIM)     // 311296
#define NPTS 40000
#define KNN  9
#define PIXR 256             // index range of pixel coords (0..255)
#define EPSF 1e-5f

typedef __attribute__((ext_vector_type(8))) short bf16x8;
typedef __attribute__((ext_vector_type(4))) float f32x4;

static __device__ __forceinline__ unsigned short f2bf(float f) {
    unsigned int u = __float_as_uint(f);
    u += 0x7FFFu + ((u >> 16) & 1u);     // round-nearest-even
    return (unsigned short)(u >> 16);
}

// ---------------------------------------------------------------------------
// Kernel 1: prep — feature transpose (1024 blocks) + workspace init side-jobs
// (winner=-1, sums=0). Stream order guarantees init before point_k.
// ---------------------------------------------------------------------------
__global__ __launch_bounds__(256) void prep_k(const float* __restrict__ feat,
                                              float* __restrict__ feat_t,
                                              int* __restrict__ winner,
                                              float* __restrict__ sums) {
    __shared__ float tile[64][65];
    const int iy   = blockIdx.x >> 2;
    const int ixb  = (blockIdx.x & 3) * 64;
    const int lane = threadIdx.x & 63;
    const int w    = threadIdx.x >> 6;

    const int tid = blockIdx.x * 256 + threadIdx.x;
    if (tid < PIXR * PIXR) winner[tid] = -1;
    if (tid < 128) sums[tid] = 0.f;

#pragma unroll
    for (int r = 0; r < 16; ++r) {
        int cc = w * 16 + r;
        tile[cc][lane] = feat[cc * HWC + iy * WDIM + ixb + lane];   // 256B coalesced
    }
    __syncthreads();
#pragma unroll
    for (int r = 0; r < 16; ++r) {
        int ix = w * 16 + r;
        feat_t[(iy * PIXR + ixb + ix) * 64 + lane] = tile[lane][ix]; // 256B coalesced
    }
}

// ---------------------------------------------------------------------------
// Kernel 2: MFMA point kernel. 4 waves/block (256 thr), 16 points/wave,
// grid 625 (64 pts/block) — few fat blocks (R5-R8 showed ~30ns/workgroup
// overhead wall at 1250-10000 small blocks). Per-wave logic = proven R7,
// plus in-wave software pipeline: fval gathers + phase A for g+1 issued
// before phase B of g (hl double-buffered; DS pipe in-order, wave-private,
// no barriers). conv fragments (bcv) loaded after the g-loop to cap
// loop-body VGPR pressure.
// ---------------------------------------------------------------------------
__global__ __launch_bounds__(256) void point_k(
    const float* __restrict__ feat_t,   // [256*256, 64]
    const float* __restrict__ diff,     // [N, 9, 3]
    const int*   __restrict__ nnpix,    // [N, 9, 2]
    const int*   __restrict__ pix,      // [N, 2]
    const float* __restrict__ W1,       // [3, 32]
    const float* __restrict__ b1,       // [32]
    const float* __restrict__ W2,       // [32, 64]
    const float* __restrict__ b2,       // [64]
    const float* __restrict__ conv_w,   // [64, 64] (out, in)
    const float* __restrict__ conv_b,   // [64]
    int*   __restrict__ winner,         // [256*256]
    float* __restrict__ y_buf,          // [N, 64]
    float* __restrict__ sums)           // [128]
{
    __shared__ float dstage[4][448];          // diff, 16 pts (432 used), per wave
    __shared__ int   npx[4][288];             // nnpix, 16 pts, per wave
    __shared__ unsigned int hl[4][2][320];    // hmid, double-buffered, 80B row stride
    __shared__ float part[4][256];            // [64 c'][4 quads] per wave
    __shared__ unsigned short msgst[4][1152]; // msg [16 pts][72 u16] per wave

    const int l   = threadIdx.x & 63;
    const int w   = __builtin_amdgcn_readfirstlane(threadIdx.x >> 6);
    const int q   = l >> 4;
    const int col = l & 15;
    const int nbase = blockIdx.x * 64 + w * 16;   // wave's 16 points

    // winner side-job: one thread per point of this block (64 points)
    if (threadIdx.x < 64) {
        int n = blockIdx.x * 64 + threadIdx.x;
        int px = pix[2 * n];
        int py = pix[2 * n + 1];
        atomicMax(&winner[py * PIXR + px], n);
    }

    // ---- persistent fragments for the g-loop ----
    // W2 B-frag: B[j = 8q+t][c' = col+16m]
    bf16x8 bw2[4];
#pragma unroll
    for (int m = 0; m < 4; ++m)
#pragma unroll
        for (int t = 0; t < 8; ++t)
            bw2[m][t] = (short)f2bf(W2[(q * 8 + t) * 64 + col + 16 * m]);
    float b2m[4];
#pragma unroll
    for (int m = 0; m < 4; ++m) b2m[m] = b2[col + 16 * m];

    // W1 columns for phase A (j0 = 2*col, j0+1)
    const int j0 = 2 * col;
    const float wa0 = W1[j0],     wa1 = W1[32 + j0],     wa2 = W1[64 + j0],     ba = b1[j0];
    const float wb0 = W1[j0 + 1], wb1 = W1[32 + j0 + 1], wb2 = W1[64 + j0 + 1], bb = b1[j0 + 1];

    // preload diff (432 f32) + nnpix (288 i32) for the wave's 16 points
#pragma unroll
    for (int t = 0; t < 7; ++t) { int idx = l + 64 * t; if (idx < 432) dstage[w][idx] = diff[nbase * 27 + idx]; }
#pragma unroll
    for (int t = 0; t < 5; ++t) { int idx = l + 64 * t; if (idx < 288) npx[w][idx] = nnpix[nbase * 18 + idx]; }

    // zero hmid pad rows 9..15 in BOTH buffers
    for (int z = 180 + l; z < 320; z += 64) { hl[w][0][z] = 0; hl[w][1][z] = 0; }

    float s1[4] = {0.f, 0.f, 0.f, 0.f}, s2[4] = {0.f, 0.f, 0.f, 0.f};
    float fvc[4][4], fvn[4][4];

    // ---- pipeline prologue: gathers + phase A for g=0 ----
#pragma unroll
    for (int i = 0; i < 4; ++i) {
        int k = q * 4 + i;
#pragma unroll
        for (int m = 0; m < 4; ++m) fvc[m][i] = 0.f;
        if (k < 9) {
            int px = npx[w][k * 2];
            int py = npx[w][k * 2 + 1];
            const float* fb = feat_t + (py * PIXR + px) * 64 + col;
#pragma unroll
            for (int m = 0; m < 4; ++m) fvc[m][i] = fb[16 * m];
        }
    }
#pragma unroll
    for (int i2 = 0; i2 < 3; ++i2) {
        int k2 = q + 4 * i2;
        if (k2 < 9) {
            float d0 = dstage[w][k2 * 3];
            float d1 = dstage[w][k2 * 3 + 1];
            float d2 = dstage[w][k2 * 3 + 2];
            float h0 = fmaxf(fmaf(d0, wa0, fmaf(d1, wa1, fmaf(d2, wa2, ba))), 0.f);
            float h1 = fmaxf(fmaf(d0, wb0, fmaf(d1, wb1, fmaf(d2, wb2, bb))), 0.f);
            hl[w][0][k2 * 20 + col] = (unsigned int)f2bf(h0) | ((unsigned int)f2bf(h1) << 16);
        }
    }

    for (int g = 0; g < 16; ++g) {
        // --- issue gathers + phase A for g+1 (consumed next iteration) ---
        if (g < 15) {
            const int gn = g + 1;
#pragma unroll
            for (int i = 0; i < 4; ++i) {
                int k = q * 4 + i;
#pragma unroll
                for (int m = 0; m < 4; ++m) fvn[m][i] = 0.f;
                if (k < 9) {
                    int px = npx[w][(gn * 9 + k) * 2];
                    int py = npx[w][(gn * 9 + k) * 2 + 1];
                    const float* fb = feat_t + (py * PIXR + px) * 64 + col;
#pragma unroll
                    for (int m = 0; m < 4; ++m) fvn[m][i] = fb[16 * m];
                }
            }
            unsigned int* hln = hl[w][gn & 1];
#pragma unroll
            for (int i2 = 0; i2 < 3; ++i2) {
                int k2 = q + 4 * i2;
                if (k2 < 9) {
                    float d0 = dstage[w][gn * 27 + k2 * 3];
                    float d1 = dstage[w][gn * 27 + k2 * 3 + 1];
                    float d2 = dstage[w][gn * 27 + k2 * 3 + 2];
                    float h0 = fmaxf(fmaf(d0, wa0, fmaf(d1, wa1, fmaf(d2, wa2, ba))), 0.f);
                    float h1 = fmaxf(fmaf(d0, wb0, fmaf(d1, wb1, fmaf(d2, wb2, bb))), 0.f);
                    hln[k2 * 20 + col] = (unsigned int)f2bf(h0) | ((unsigned int)f2bf(h1) << 16);
                }
            }
        }

        // --- phase B(g): wts via MFMA, weighted neighbor sum ---
        bf16x8 a;
        {
            uint4 av = *(const uint4*)((const char*)hl[w][g & 1] + col * 80 + q * 16);
            a = __builtin_bit_cast(bf16x8, av);
        }
#pragma unroll
        for (int m = 0; m < 4; ++m) {
            f32x4 acc = {b2m[m], b2m[m], b2m[m], b2m[m]};
            acc = __builtin_amdgcn_mfma_f32_16x16x32_bf16(a, bw2[m], acc, 0, 0, 0);
            float p = 0.f;
#pragma unroll
            for (int i = 0; i < 4; ++i)
                p = fmaf(fmaxf(acc[i], 0.f), fvc[m][i], p);
            part[w][(col + 16 * m) * 4 + q] = p;     // quad partials
        }
        float4 pr = *(const float4*)&part[w][l * 4]; // lane l = channel c'
        float msg = (pr.x + pr.y) + (pr.z + pr.w);
        msgst[w][g * 72 + l] = f2bf(msg);

        // rotate pipeline registers
#pragma unroll
        for (int i = 0; i < 4; ++i)
#pragma unroll
            for (int m = 0; m < 4; ++m) fvc[m][i] = fvn[m][i];
    }

    // ---- phase C: batched 1x1 conv over the wave's 16 points ----
    // conv B-frag loaded here (not before the loop) to cap loop VGPR pressure.
    bf16x8 bcv[4][2];
#pragma unroll
    for (int m = 0; m < 4; ++m)
#pragma unroll
        for (int h = 0; h < 2; ++h)
#pragma unroll
            for (int t = 0; t < 8; ++t)
                bcv[m][h][t] = (short)f2bf(conv_w[(col + 16 * m) * 64 + h * 32 + q * 8 + t]);
    float cbm[4];
#pragma unroll
    for (int m = 0; m < 4; ++m) cbm[m] = conv_b[col + 16 * m];

    bf16x8 am[2];
#pragma unroll
    for (int h = 0; h < 2; ++h) {
        uint4 av = *(const uint4*)((const char*)msgst[w] + col * 144 + h * 64 + q * 16);
        am[h] = __builtin_bit_cast(bf16x8, av);
    }
#pragma unroll
    for (int m = 0; m < 4; ++m) {
        f32x4 acc = {cbm[m], cbm[m], cbm[m], cbm[m]};
        acc = __builtin_amdgcn_mfma_f32_16x16x32_bf16(am[0], bcv[m][0], acc, 0, 0, 0);
        acc = __builtin_amdgcn_mfma_f32_16x16x32_bf16(am[1], bcv[m][1], acc, 0, 0, 0);
#pragma unroll
        for (int i = 0; i < 4; ++i) {
            float y = acc[i];                        // row n_local = 4q+i, col c
            y_buf[(nbase + q * 4 + i) * 64 + col + 16 * m] = y;
            s1[m] += y;
            s2[m] = fmaf(y, y, s2[m]);
        }
    }

    // ---- BN partials: cross-quad shfl reduce, atomics from quad 0 ----
#pragma unroll
    for (int m = 0; m < 4; ++m) {
        float a1 = s1[m], a2 = s2[m];
        a1 += __shfl_xor(a1, 16); a1 += __shfl_xor(a1, 32);
        a2 += __shfl_xor(a2, 16); a2 += __shfl_xor(a2, 32);
        if (q == 0) {
            atomicAdd(&sums[col + 16 * m], a1);
            atomicAdd(&sums[64 + col + 16 * m], a2);
        }
    }
}

// ---------------------------------------------------------------------------
// Kernel 3: full-image writer, c-chunked. Block = (y row, 16-c chunk).
// Each lane loads its winner's 64B y_buf chunk line ONCE (4x float4), then
// reuses it across the 16 channels. All stores coalesced.
// ---------------------------------------------------------------------------
__global__ __launch_bounds__(256) void write_k(
    const float* __restrict__ y_buf,   // [N, 64] pre-BN
    const float* __restrict__ sums,    // [128]
    const float* __restrict__ gamma,   // [64]
    const float* __restrict__ beta,    // [64]
    const int*   __restrict__ winner,  // [256*256]
    float* __restrict__ out)           // [64, 256, 1216]
{
    const int y  = blockIdx.x >> 2;
    const int ch = (blockIdx.x & 3) * 16;
    const int t  = threadIdx.x;
    const float inv_n = 1.f / (float)NPTS;

    const int wn = winner[y * PIXR + t];       // coalesced 1KB, kept in VGPR
    float4 yl[4] = {{0,0,0,0},{0,0,0,0},{0,0,0,0},{0,0,0,0}};
    if (wn >= 0) {
        const float4* yp = (const float4*)(y_buf + wn * 64 + ch);  // 64B line
        yl[0] = yp[0]; yl[1] = yp[1]; yl[2] = yp[2]; yl[3] = yp[3];
    }
    const float* ylf = (const float*)yl;

#pragma unroll
    for (int cc = 0; cc < 16; ++cc) {
        int c = ch + cc;
        float mean = sums[c] * inv_n;
        float var  = sums[64 + c] * inv_n - mean * mean;
        float rstd = rsqrtf(var + EPSF);
        float A = gamma[c] * rstd;
        float B = beta[c] - mean * A;

        float v = (wn >= 0) ? fmaxf(fmaf(A, ylf[cc], B), 0.f) : 0.f;
        float* row = out + c * HWC + y * WDIM;
        row[t] = v;                            // coalesced 1KB
        if (t < 240) {
            float4 z = {0.f, 0.f, 0.f, 0.f};
            ((float4*)(row + 256))[t] = z;     // zero x = 256..1215
        }
    }
}

// ---------------------------------------------------------------------------
extern "C" void kernel_launch(void* const* d_in, const int* in_sizes, int n_in,
                              void* d_out, int out_size, void* d_ws, size_t ws_size,
                              hipStream_t stream) {
    const float* feat   = (const float*)d_in[0];   // [1,64,256,1216]
    const float* diff   = (const float*)d_in[1];   // [1,40000,9,3]
    const int*   pix    = (const int*)  d_in[2];   // [1,40000,2]
    const int*   nnpix  = (const int*)  d_in[3];   // [1,40000,9,2]
    const float* W1     = (const float*)d_in[4];   // [3,32]
    const float* b1v    = (const float*)d_in[5];   // [32]
    const float* W2     = (const float*)d_in[6];   // [32,64]
    const float* b2v    = (const float*)d_in[7];   // [64]
    const float* conv_w = (const float*)d_in[8];   // [64,64]
    const float* conv_b = (const float*)d_in[9];   // [64]
    const float* gamma  = (const float*)d_in[10];  // [64]
    const float* beta   = (const float*)d_in[11];  // [64]
    float* out = (float*)d_out;

    // workspace layout (bytes) — within proven 37.5 MB footprint:
    //   feat_t : 0        .. 16777216    (256*256*64 f32)
    //   y_buf  : 16777216 .. 27017216    (40000*64 f32)
    //   sums   : 27017216 .. 27017728    (128 f32)
    //   winner : 27017728 .. 27279872    (256*256 i32)
    char* ws = (char*)d_ws;
    float* feat_t  = (float*)(ws);
    float* y_buf   = (float*)(ws + 16777216);
    float* sums    = (float*)(ws + 27017216);
    int*   winner  = (int*)  (ws + 27017728);

    prep_k<<<1024, 256, 0, stream>>>(feat, feat_t, winner, sums);
    point_k<<<625, 256, 0, stream>>>(feat_t, diff, nnpix, pix, W1, b1v, W2, b2v,
                                     conv_w, conv_b, winner, y_buf, sums);
    write_k<<<1024, 256, 0, stream>>>(y_buf, sums, gamma, beta, winner, out);
}